// Round 14
// baseline (454.186 us; speedup 1.0000x reference)
//
#include <hip/hip_runtime.h>

#define NCH 6
#define NX 32
#define PLANE 1024
#define NCELL (NX * PLANE)
#define STEP_STRIDE (NCH * NCELL)
#define NTHREADS 512                // 2 planes x 8 rows x 32 z, 1 thread/cell
#define NBLOCKS 64                  // 16 x-chunks x 4 y-stripes
#define RB 8                        // ring slots; slot = e&7, 2-bit sign tag = (e>>2)&3 -> e mod 32
#define MLEAD 6                     // max publish lead over neighbor prog (<= RB-2: a reader
                                    // lagging 7 blocks the slot-overwrite; skew<=6 << 16 tag-safe)

#define RING_WORDS ((size_t)RB * 3 * NCELL)
#define F_DONE 0
#define F_PROG 16                   // prog[b] at flags[F_PROG + b*16]

typedef unsigned long long u64;

__device__ __forceinline__ u64 ld64(const u64* p) {
    return __hip_atomic_load(p, __ATOMIC_RELAXED, __HIP_MEMORY_SCOPE_SYSTEM);
}
__device__ __forceinline__ void st64(u64* p, u64 v) {
    __hip_atomic_store(p, v, __ATOMIC_RELAXED, __HIP_MEMORY_SCOPE_SYSTEM);
}
__device__ __forceinline__ int ldi(const int* p) {
    return __hip_atomic_load(p, __ATOMIC_RELAXED, __HIP_MEMORY_SCOPE_SYSTEM);
}
__device__ __forceinline__ void sti(int* p, int v) {
    __hip_atomic_store(p, v, __ATOMIC_RELAXED, __HIP_MEMORY_SCOPE_SYSTEM);
}
__device__ __forceinline__ u64 pack2(float a, float b) {
    return ((u64)__float_as_uint(b) << 32) | __float_as_uint(a);
}
__device__ __forceinline__ u64 pack2t(float a, float b, unsigned tg) {
    u64 w = pack2(a, b);                       // a,b in [0,1] -> signs are 0
    if (tg & 1u) w |= 0x80000000ULL;           // low sign  = tag bit 0
    if (tg & 2u) w |= 0x8000000000000000ULL;   // high sign = tag bit 1
    return w;
}
__device__ __forceinline__ bool tagchk(u64 w, unsigned tg) {
    return ((((unsigned)(w >> 31)) & 1u) == (tg & 1u)) &
           ((((unsigned)(w >> 63)) & 1u) == (tg >> 1));
}
__device__ __forceinline__ void unpack2(u64 w, float* d0, float* d1) {
    *d0 = __uint_as_float((unsigned)w & 0x7fffffffu);
    *d1 = __uint_as_float((unsigned)(w >> 32) & 0x7fffffffu);
}

// Distance-gated free-running dataflow. phi_t(c)=0 for t<dist(c) (all
// couplings positive, speed 1) -> halo ring reads gated on t>=dist: zero-land
// blocks never poll and free-run at LDS speed, overlapping their mandatory
// history writes with the front's RT-paced chain (the only true dependency:
// ~18 cross-block hops seed->target). Tag mod-32 + MLEAD throttle bound
// adjacent skew <=6 -> tag disambiguation and slot reuse provably safe.
__global__ void __launch_bounds__(NTHREADS)
BEMNA_V7_2_PhaseSpace_44117904064519_kernel(
    const float* __restrict__ D,
    const int* __restrict__ sx_p, const int* __restrict__ sy_p,
    const int* __restrict__ sz_p, const int* __restrict__ ex_p,
    const int* __restrict__ ey_p, const int* __restrict__ ez_p,
    const int* __restrict__ maxit_p,
    float* __restrict__ out,
    u64* __restrict__ ring,
    int* __restrict__ flags)
{
    __shared__ u64 Tb[2][3][NTHREADS];   // ping-pong phi tile, u64-packed (24 KB)
    __shared__ int lds_dn;
    volatile int* vdn = &lds_dn;

    const int tid  = (int)threadIdx.x;
    const int bx   = (int)blockIdx.x;
    const int cx   = bx >> 2;            // x-chunk (2 planes)
    const int st   = bx & 3;             // y-stripe (8 rows)
    const int lx   = tid >> 8;           // plane within chunk
    const int row  = (tid >> 5) & 7;
    const int z    = tid & 31;
    const int lane = tid & 63;           // wave = 2 adjacent rows of one plane
    const int gx   = (cx << 1) + lx;
    const int gy   = (st << 3) + row;
    const int cell = (gx << 10) + (gy << 5) + z;

    const int sx = *sx_p, sy = *sy_p, sz = *sz_p;
    const int ex = *ex_p, ey = *ey_p, ez = *ez_p;
    const int maxit = *maxit_p;
    const bool is_seed   = (cell == ((sx << 10) | (sy << 5) | sz));
    const bool is_target = (cell == ((ex << 10) | (ey << 5) | ez));

    // cross-block ring duties (each thread: 1 x-side; rows 0/7: 1 y-side)
    const bool has_x = lx ? (gx <= 30) : (gx >= 1);
    const int  gxh   = lx ? gx + 1 : gx - 1;
    const int  cellx = has_x ? ((gxh << 10) + (gy << 5) + z) : cell;
    const int  distx = abs(gxh - sx) + abs(gy - sy) + abs(z - sz);
    const bool has_y = (row == 0) ? (gy >= 1) : ((row == 7) ? (gy <= 30) : false);
    const int  gyh   = (row == 0) ? gy - 1 : gy + 1;
    const int  celly = has_y ? ((gx << 10) + (gyh << 5) + z) : cell;
    const int  disty = abs(gx - sx) + abs(gyh - sy) + abs(z - sz);

    // LDS neighbor addresses (internal x side; cross-pair y side)
    const int xin = lx ? tid - 256 : tid + 256;
    const int yin = ((row & 1) ? tid + 32 : tid - 32) & (NTHREADS - 1);

    // D coefficients (zeroed out-of-bounds; mask all clamped/garbage lanes)
    const int  nbg[NCH] = { cell - PLANE, cell + PLANE, cell - 32, cell + 32, cell - 1, cell + 1 };
    const bool okn[NCH] = { gx >= 1, gx <= 30, gy >= 1, gy <= 30, z >= 1, z <= 30 };
    float dreg[NCH][NCH];
#pragma unroll
    for (int o = 0; o < NCH; ++o)
#pragma unroll
        for (int i = 0; i < NCH; ++i)
            dreg[o][i] = okn[o] ? D[(size_t)(o * NCH + i) * NCELL + nbg[o]] + 0.95f : 0.0f;

    // ---- init: epoch 0 (slot 0, tag 0), tile[0], history slice 0, prog 0 ----
    float myv[NCH];
    const float iv = is_seed ? 1.0f : 0.0f;
    {
        const u64 p = pack2(iv, iv);     // tag(0) = 0 -> plain
        st64(&ring[0 * NCELL + cell], p);
        st64(&ring[1 * NCELL + cell], p);
        st64(&ring[2 * NCELL + cell], p);
        Tb[0][0][tid] = p; Tb[0][1][tid] = p; Tb[0][2][tid] = p;
#pragma unroll
        for (int o = 0; o < NCH; ++o) { myv[o] = iv; out[o * NCELL + cell] = iv; }
    }
    if (tid == 0) { lds_dn = -1; sti(&flags[F_PROG + bx * 16], 0); }
    __syncthreads();

    int tripped = 0, lastmin = 0;
    for (int t = 0; t <= maxit - 2; ++t) {
        const u64* rs = ring + (size_t)(t & (RB - 1)) * 3 * NCELL;
        const unsigned tg = (unsigned)((t >> 2) & 3);

        // ---- distance-gated halo poll (data IS the flag; batched loads) ----
        const bool needx = has_x && (t >= distx);
        const bool needy = has_y && (t >= disty);
        float rx[NCH] = {0,0,0,0,0,0}, ry[NCH] = {0,0,0,0,0,0};
        if (__ballot(needx || needy) != 0ull) {
            u64 hx0 = 0, hx1 = 0, hx2 = 0, hy0 = 0, hy1 = 0, hy2 = 0;
            for (;;) {
                if (needx) { hx0 = ld64(rs + cellx); hx1 = ld64(rs + NCELL + cellx); hx2 = ld64(rs + 2 * NCELL + cellx); }
                if (needy) { hy0 = ld64(rs + celly); hy1 = ld64(rs + NCELL + celly); hy2 = ld64(rs + 2 * NCELL + celly); }
                if (lane == 0) { const int dnv = ldi(&flags[F_DONE]); if (dnv >= 0) *vdn = dnv; }
                bool okr = true;
                if (needx) okr = okr & tagchk(hx0, tg) & tagchk(hx1, tg) & tagchk(hx2, tg);
                if (needy) okr = okr & tagchk(hy0, tg) & tagchk(hy1, tg) & tagchk(hy2, tg);
                const int d = *vdn;
                if (d >= 0 && t + 1 > d) break;
                if (__ballot(okr) == ~0ull) break;
                __builtin_amdgcn_s_sleep(1);
            }
            if (needx) { unpack2(hx0, &rx[0], &rx[1]); unpack2(hx1, &rx[2], &rx[3]); unpack2(hx2, &rx[4], &rx[5]); }
            if (needy) { unpack2(hy0, &ry[0], &ry[1]); unpack2(hy1, &ry[2], &ry[3]); unpack2(hy2, &ry[4], &ry[5]); }
        } else if (((t & 3) == 0) && lane == 0) {   // free-run: cheap dn duty
            const int dnv = ldi(&flags[F_DONE]); if (dnv >= 0) *vdn = dnv;
        }

        // ---- lead throttle (tid0; off critical path, ~1 check / MLEAD epochs)
        if (tid == 0 && (t + 1 - lastmin > MLEAD)) {
            for (;;) {
                int mn = 0x7fffffff;
                if (cx > 0)  mn = min(mn, ldi(&flags[F_PROG + (bx - 4) * 16]));
                if (cx < 15) mn = min(mn, ldi(&flags[F_PROG + (bx + 4) * 16]));
                if (st > 0)  mn = min(mn, ldi(&flags[F_PROG + (bx - 1) * 16]));
                if (st < 3)  mn = min(mn, ldi(&flags[F_PROG + (bx + 1) * 16]));
                const int dnv = ldi(&flags[F_DONE]); if (dnv >= 0) *vdn = dnv;
                const int d = *vdn;
                if (d >= 0 && t + 1 > d) break;
                if (mn >= t + 1 - MLEAD) { lastmin = mn; break; }
                __builtin_amdgcn_s_sleep(2);
            }
        }
        __syncthreads();                           // halo+dn settled; tile[t&1] ready
        { const int d = *vdn; if (d >= 0 && t + 1 > d) break; }   // uniform abort

        // ---- gather neighbors: LDS (internal x, cross-pair y) + shuffles ----
        float LX[NCH], LY[NCH];
        {
            const u64 q0 = Tb[t & 1][0][xin], q1 = Tb[t & 1][1][xin], q2 = Tb[t & 1][2][xin];
            unpack2(q0, &LX[0], &LX[1]); unpack2(q1, &LX[2], &LX[3]); unpack2(q2, &LX[4], &LX[5]);
            const u64 p0 = Tb[t & 1][0][yin], p1 = Tb[t & 1][1][yin], p2 = Tb[t & 1][2][yin];
            unpack2(p0, &LY[0], &LY[1]); unpack2(p1, &LY[2], &LY[3]); unpack2(p2, &LY[4], &LY[5]);
        }
        const bool odd = (row & 1) != 0;
        float v[NCH];
        {
            float s0 = 0.f, s1 = 0.f, s2 = 0.f, s3 = 0.f, s4 = 0.f, s5 = 0.f;
#pragma unroll
            for (int i = 0; i < NCH; ++i) {
                const float pairv = __shfl(myv[i], lane ^ 32);          // y within wave pair
                const float zmv   = __shfl(myv[i], (lane + 63) & 63);   // z-1 (edge masked by dreg)
                const float zpv   = __shfl(myv[i], (lane + 1) & 63);    // z+1
                const float xmv = lx ? LX[i] : rx[i];
                const float xpv = lx ? rx[i] : LX[i];
                const float ymv = odd ? pairv : (row > 0 ? LY[i] : ry[i]);
                const float ypv = odd ? (row < 7 ? LY[i] : ry[i]) : pairv;
                s0 = fmaf(dreg[0][i], xmv, s0);
                s1 = fmaf(dreg[1][i], xpv, s1);
                s2 = fmaf(dreg[2][i], ymv, s2);
                s3 = fmaf(dreg[3][i], ypv, s3);
                s4 = fmaf(dreg[4][i], zmv, s4);
                s5 = fmaf(dreg[5][i], zpv, s5);
            }
            v[0] = fminf(fmaxf(s0, 0.f), 1.f);
            v[1] = fminf(fmaxf(s1, 0.f), 1.f);
            v[2] = fminf(fmaxf(s2, 0.f), 1.f);
            v[3] = fminf(fmaxf(s3, 0.f), 1.f);
            v[4] = fminf(fmaxf(s4, 0.f), 1.f);
            v[5] = fminf(fmaxf(s5, 0.f), 1.f);
        }

        if (is_target && !tripped &&
            (v[0] + v[1] + v[2] + v[3] + v[4] + v[5] > 0.01f)) {
            sti(&flags[F_DONE], t + 1);
            tripped = 1;
        }

        // ---- publish epoch t+1: tagged ring + tile + history + prog ----
        {
            const unsigned tg1 = (unsigned)(((t + 1) >> 2) & 3);
            u64* wsl = ring + (size_t)((t + 1) & (RB - 1)) * 3 * NCELL;
            st64(wsl + cell,             pack2t(v[0], v[1], tg1));
            st64(wsl + NCELL + cell,     pack2t(v[2], v[3], tg1));
            st64(wsl + 2 * NCELL + cell, pack2t(v[4], v[5], tg1));
            Tb[(t + 1) & 1][0][tid] = pack2(v[0], v[1]);
            Tb[(t + 1) & 1][1][tid] = pack2(v[2], v[3]);
            Tb[(t + 1) & 1][2][tid] = pack2(v[4], v[5]);
            float* op = out + (size_t)(t + 1) * STEP_STRIDE + cell;
#pragma unroll
            for (int o = 0; o < NCH; ++o) op[o * NCELL] = v[o];
        }
        if (tid == 0) sti(&flags[F_PROG + bx * 16], t + 1);
        __syncthreads();                           // tile[t+1] complete
#pragma unroll
        for (int o = 0; o < NCH; ++o) myv[o] = v[o];
    }
}

// Read-once/write-many 2D fill: slices > tf := out[tf] (incl. overshoot).
__global__ void fill_kernel(const int* __restrict__ flags,
                            float4* __restrict__ out,
                            int total4)
{
    const int s4 = STEP_STRIDE / 4;
    const int maxit = total4 / s4;
    const int ds = flags[F_DONE];
    const int tf = (ds >= 1 && ds <= maxit - 1) ? ds : maxit - 1;
    const int idx = (int)blockIdx.x * (int)blockDim.x + (int)threadIdx.x;
    const float4 v = out[(size_t)tf * s4 + idx];
    for (int t = tf + 1 + (int)blockIdx.y; t < maxit; t += (int)gridDim.y)
        out[(size_t)t * s4 + idx] = v;
}

extern "C" void kernel_launch(void* const* d_in, const int* in_sizes, int n_in,
                              void* d_out, int out_size, void* d_ws, size_t ws_size,
                              hipStream_t stream)
{
    const float* D   = (const float*)d_in[0];
    const int* sx    = (const int*)d_in[1];
    const int* sy    = (const int*)d_in[2];
    const int* sz    = (const int*)d_in[3];
    const int* ex    = (const int*)d_in[4];
    const int* ey    = (const int*)d_in[5];
    const int* ez    = (const int*)d_in[6];
    const int* maxit = (const int*)d_in[7];
    float* out = (float*)d_out;

    u64* ring  = (u64*)d_ws;                   // 8 x 3 x 32768 x 8B = 6.3 MB
    int* flags = (int*)(ring + RING_WORDS);

    // 64 blocks x 512 threads (2 planes x 8 rows), distance-gated dataflow.
    // Plain launch; co-residency by capacity (64 blocks << 256 CUs).
    BEMNA_V7_2_PhaseSpace_44117904064519_kernel<<<dim3(NBLOCKS), dim3(NTHREADS), 0, stream>>>(
        D, sx, sy, sz, ex, ey, ez, maxit, out, ring, flags);

    const int total4 = out_size / 4;
    fill_kernel<<<dim3((STEP_STRIDE / 4) / 256, 8), dim3(256), 0, stream>>>(
        flags, (float4*)out, total4);
}

// Round 15
// 402.573 us; speedup vs baseline: 1.1282x; 1.1282x over previous
//
#include <hip/hip_runtime.h>

#define NCH 6
#define NX 32
#define PLANE 1024                  // 32x32 cells per x-plane
#define NCELL (NX * PLANE)
#define STEP_STRIDE (NCH * NCELL)   // floats per history slice
#define NTHREADS 256                // one y-stripe (8 rows x 32 z) of a plane
#define NBLOCKS 128                 // 32 planes x 4 y-stripes
#define RB 2                        // ring slots; (slot, sign-parity) = epoch mod 4

// ws: u64 ring[RB][3][NCELL] SoA streams (stream k = channels 2k,2k+1), then
// int flags. Epoch tag = sign bits (phi in [0,1] post-clip -> sign always 0):
// producer ORs parity P=(e>>1)&1 into both sign bits; (slot=e&1, P) = e mod 4.
// Mutual neighbor dependency bounds skew<=1, so only {t, t-2} can occupy a
// slot -> 1-bit parity disambiguates (R9/R10/R11-proven, absmax 0). Poison
// 0xAA.. has sign=1 and every record is rewritten before its first parity-1
// check -> bootstrap-safe with zero init. Loads are issued unconditionally
// per poll round (batched -> 1 L3 RT), tags checked afterwards (R10 lesson;
// R9's conditional per-word polling serialized 12 RTs and regressed).
//
// SESSION LEDGER (why this exact structure): six sync structures measured —
// global barrier 2.36, block-flag 2.0, per-thread mailboxes 4.5, THIS
// (wave-batched tagged dataflow w/ LDS tile) 2.0, k=2 temporal 5.0/superstep,
// distance-gated 2.6 us/step. ~2 us/step is the publish->detect exchange
// floor on MI355X; 89-step serial chain -> stepper ~182 us is at that floor.
#define RING_WORDS ((size_t)RB * 3 * NCELL)
#define F_DONE 0

typedef unsigned long long u64;

__device__ __forceinline__ u64 ld64(const u64* p) {
    return __hip_atomic_load(p, __ATOMIC_RELAXED, __HIP_MEMORY_SCOPE_SYSTEM);
}
__device__ __forceinline__ void st64(u64* p, u64 v) {
    __hip_atomic_store(p, v, __ATOMIC_RELAXED, __HIP_MEMORY_SCOPE_SYSTEM);
}
__device__ __forceinline__ int ldi(const int* p) {
    return __hip_atomic_load(p, __ATOMIC_RELAXED, __HIP_MEMORY_SCOPE_SYSTEM);
}
__device__ __forceinline__ void sti(int* p, int v) {
    __hip_atomic_store(p, v, __ATOMIC_RELAXED, __HIP_MEMORY_SCOPE_SYSTEM);
}
__device__ __forceinline__ u64 pack2p(float a, float b, unsigned P) {
    const u64 w = ((u64)__float_as_uint(b) << 32) | __float_as_uint(a);
    return P ? (w | 0x8000000080000000ULL) : w;
}
__device__ __forceinline__ bool tagok(u64 w, unsigned P) {
    return (((unsigned)(w >> 63)) == P) & ((((unsigned)w) >> 31) == P);
}
__device__ __forceinline__ void unpack2(u64 w, float* d0, float* d1) {
    *d0 = __uint_as_float((unsigned)w & 0x7fffffffu);
    *d1 = __uint_as_float((unsigned)(w >> 32) & 0x7fffffffu);
}

__global__ void __launch_bounds__(NTHREADS)
BEMNA_V7_2_PhaseSpace_44117904064519_kernel(
    const float* __restrict__ D,
    const int* __restrict__ sx_p, const int* __restrict__ sy_p,
    const int* __restrict__ sz_p, const int* __restrict__ ex_p,
    const int* __restrict__ ey_p, const int* __restrict__ ez_p,
    const int* __restrict__ maxit_p,
    float* __restrict__ out,
    u64* __restrict__ ring,
    int* __restrict__ flags)
{
    __shared__ float tile[2][NCH][NTHREADS];   // ping-pong own stripe
    __shared__ int lds_dn;
    volatile int* vdn = &lds_dn;

    const int tid = (int)threadIdx.x;          // yl*32+z
    const int bx  = (int)blockIdx.x;
    const int x   = bx >> 2;                   // plane
    const int s   = bx & 3;                    // y-stripe
    const int yl  = tid >> 5;                  // 0..7
    const int z   = tid & 31;
    const int y   = (s << 3) + yl;
    const int cell = (x << 10) + (y << 5) + z;

    const int sx = *sx_p, sy = *sy_p, sz = *sz_p;
    const int ex = *ex_p, ey = *ey_p, ez = *ez_p;
    const int maxit = *maxit_p;
    const bool is_seed   = (cell == ((sx << 10) | (sy << 5) | sz));
    const bool is_target = (cell == ((ex << 10) | (ey << 5) | ez));

    // o=0 reads (x-1); o=1 (x+1); o=2 (y-1); o=3 (y+1); o=4 (z-1); o=5 (z+1)
    const int  nbg[NCH] = { cell - PLANE, cell + PLANE, cell - 32, cell + 32, cell - 1, cell + 1 };
    const bool ok[NCH]  = { x >= 1, x <= 30, y >= 1, y <= 30, z >= 1, z <= 30 };
    const int izm = (tid - 1) & (NTHREADS - 1), izp = (tid + 1) & (NTHREADS - 1);

    // halo groups this thread needs from the ring
    const bool has_xm = (x >= 1), has_xp = (x <= 30);
    const bool has_ym = (yl == 0) && (y >= 1);
    const bool has_yp = (yl == 7) && (y <= 30);

    // D step-invariant: 36 coefficients in registers (zeroed out-of-bounds)
    float dreg[NCH][NCH];
#pragma unroll
    for (int o = 0; o < NCH; ++o)
#pragma unroll
        for (int i = 0; i < NCH; ++i)
            dreg[o][i] = ok[o] ? D[(size_t)(o * NCH + i) * NCELL + nbg[o]] + 0.95f : 0.0f;

    // ---- init: epoch 0 (slot 0, parity 0 = plain), hist slice 0, tile[0] ----
    const float iv = is_seed ? 1.0f : 0.0f;
    {
        const u64 p = pack2p(iv, iv, 0);
        st64(&ring[0 * NCELL + cell], p);
        st64(&ring[1 * NCELL + cell], p);
        st64(&ring[2 * NCELL + cell], p);
        float* outp = out + cell;
#pragma unroll
        for (int o = 0; o < NCH; ++o) { outp[o * NCELL] = iv; tile[0][o][tid] = iv; }
    }
    if (tid == 0) lds_dn = -1;
    __syncthreads();                           // lds_dn + tile[0] visible

    int tripped = 0;
    // iteration t consumes epoch t, produces phi_{t+1} (= history slice t+1)
    for (int t = 0; t <= maxit - 2; ++t) {
        const u64* r0 = ring + (size_t)(t & 1) * 3 * NCELL;
        const u64* r1 = r0 + NCELL;
        const u64* r2 = r1 + NCELL;
        const unsigned P = (unsigned)((t >> 1) & 1);
        const int cm = cell - PLANE, cp = cell + PLANE;
        const int am = cell - 32,    ap = cell + 32;

        // zero-init so masked/boundary lanes never feed garbage (NaN x 0)
        u64 wa0 = 0, wa1 = 0, wa2 = 0, wb0 = 0, wb1 = 0, wb2 = 0;
        u64 wc0 = 0, wc1 = 0, wc2 = 0, wd0 = 0, wd1 = 0, wd2 = 0;
        for (;;) {
            // batched independent loads -> one waitcnt, one L3 RT per round
            if (has_xm) { wa0 = ld64(r0 + cm); wa1 = ld64(r1 + cm); wa2 = ld64(r2 + cm); }
            if (has_xp) { wb0 = ld64(r0 + cp); wb1 = ld64(r1 + cp); wb2 = ld64(r2 + cp); }
            if (has_ym) { wc0 = ld64(r0 + am); wc1 = ld64(r1 + am); wc2 = ld64(r2 + am); }
            if (has_yp) { wd0 = ld64(r0 + ap); wd1 = ld64(r1 + ap); wd2 = ld64(r2 + ap); }
            if ((tid & 63) == 0) {             // lane0/wave: done-flag duty
                const int dn = ldi(&flags[F_DONE]);
                if (dn >= 0) *vdn = dn;
            }
            // tag checks AFTER all loads are in flight
            bool okr = true;
            if (has_xm) okr = okr & tagok(wa0, P) & tagok(wa1, P) & tagok(wa2, P);
            if (has_xp) okr = okr & tagok(wb0, P) & tagok(wb1, P) & tagok(wb2, P);
            if (has_ym) okr = okr & tagok(wc0, P) & tagok(wc1, P) & tagok(wc2, P);
            if (has_yp) okr = okr & tagok(wd0, P) & tagok(wd1, P) & tagok(wd2, P);
            const int d = *vdn;                // LDS broadcast
            if (d >= 0 && t + 1 > d) break;    // abort: data moot
            if (__ballot(okr) == ~0ull) break;
            __builtin_amdgcn_s_sleep(1);
        }
        __syncthreads();                       // tile writes settled block-wide
        { const int d = *vdn; if (d >= 0 && t + 1 > d) break; }  // uniform abort

        float xm[NCH], xp[NCH], ym[NCH], yp[NCH];
        unpack2(wa0, &xm[0], &xm[1]); unpack2(wa1, &xm[2], &xm[3]); unpack2(wa2, &xm[4], &xm[5]);
        unpack2(wb0, &xp[0], &xp[1]); unpack2(wb1, &xp[2], &xp[3]); unpack2(wb2, &xp[4], &xp[5]);
        unpack2(wc0, &ym[0], &ym[1]); unpack2(wc1, &ym[2], &ym[3]); unpack2(wc2, &ym[4], &ym[5]);
        unpack2(wd0, &yp[0], &yp[1]); unpack2(wd1, &yp[2], &yp[3]); unpack2(wd2, &yp[4], &yp[5]);

        // in-stripe y neighbors from LDS (dreg masks y==0/31 edges)
        const float (*L)[NTHREADS] = tile[t & 1];
        if (!has_ym) {
            const int n = (tid - 32) & (NTHREADS - 1);
#pragma unroll
            for (int i = 0; i < NCH; ++i) ym[i] = L[i][n];
        }
        if (!has_yp) {
            const int n = (tid + 32) & (NTHREADS - 1);
#pragma unroll
            for (int i = 0; i < NCH; ++i) yp[i] = L[i][n];
        }

        float v[NCH];
        {
            float a0 = 0.f, a1 = 0.f, a2 = 0.f, a3 = 0.f, a4 = 0.f, a5 = 0.f;
#pragma unroll
            for (int i = 0; i < NCH; ++i) {
                a0 = fmaf(dreg[0][i], xm[i], a0);
                a1 = fmaf(dreg[1][i], xp[i], a1);
                a2 = fmaf(dreg[2][i], ym[i], a2);
                a3 = fmaf(dreg[3][i], yp[i], a3);
                a4 = fmaf(dreg[4][i], L[i][izm], a4);
                a5 = fmaf(dreg[5][i], L[i][izp], a5);
            }
            v[0] = fminf(fmaxf(a0, 0.f), 1.f);
            v[1] = fminf(fmaxf(a1, 0.f), 1.f);
            v[2] = fminf(fmaxf(a2, 0.f), 1.f);
            v[3] = fminf(fmaxf(a3, 0.f), 1.f);
            v[4] = fminf(fmaxf(a4, 0.f), 1.f);
            v[5] = fminf(fmaxf(a5, 0.f), 1.f);
        }

        // trip: phi_{t+1} is the frozen state -> done_step = t+1
        if (is_target && !tripped) {
            if (v[0] + v[1] + v[2] + v[3] + v[4] + v[5] > 0.01f) {
                sti(&flags[F_DONE], t + 1);
                tripped = 1;
            }
        }

        // publish epoch t+1: fire-and-forget tagged stores (no drain, no flag)
        {
            const unsigned P1 = (unsigned)(((t + 1) >> 1) & 1);
            u64* w0 = ring + (size_t)((t + 1) & 1) * 3 * NCELL;
            st64(w0 + 0 * NCELL + cell, pack2p(v[0], v[1], P1));
            st64(w0 + 1 * NCELL + cell, pack2p(v[2], v[3], P1));
            st64(w0 + 2 * NCELL + cell, pack2p(v[4], v[5], P1));
#pragma unroll
            for (int o = 0; o < NCH; ++o) tile[(t + 1) & 1][o][tid] = v[o];
        }

        // history slice t+1 last: HBM acks overlap the next poll
        {
            float* outp = out + (size_t)(t + 1) * STEP_STRIDE + cell;
#pragma unroll
            for (int o = 0; o < NCH; ++o) outp[o * NCELL] = v[o];
        }
    }
}

// Read-once/write-many fill: one float4 lane per slice element. Each thread
// loads its element of the frozen slice out[tf] once and streams it to
// slices tf+1..maxit-1 (overwriting any stepper overshoot). Write-bound.
__global__ void fill_kernel(const int* __restrict__ flags,
                            float4* __restrict__ out,
                            int total4)
{
    const int s4 = STEP_STRIDE / 4;
    const int maxit = total4 / s4;
    const int ds = flags[F_DONE];
    const int tf = (ds >= 1 && ds <= maxit - 1) ? ds : maxit - 1;
    const int idx = (int)blockIdx.x * (int)blockDim.x + (int)threadIdx.x;
    const float4 v = out[(size_t)tf * s4 + idx];
    for (int t = tf + 1; t < maxit; ++t)
        out[(size_t)t * s4 + idx] = v;
}

extern "C" void kernel_launch(void* const* d_in, const int* in_sizes, int n_in,
                              void* d_out, int out_size, void* d_ws, size_t ws_size,
                              hipStream_t stream)
{
    const float* D   = (const float*)d_in[0];
    const int* sx    = (const int*)d_in[1];
    const int* sy    = (const int*)d_in[2];
    const int* sz    = (const int*)d_in[3];
    const int* ex    = (const int*)d_in[4];
    const int* ey    = (const int*)d_in[5];
    const int* ez    = (const int*)d_in[6];
    const int* maxit = (const int*)d_in[7];
    float* out = (float*)d_out;

    u64* ring  = (u64*)d_ws;                   // 2 x 3 x 32768 x 8B = 1.6 MB
    int* flags = (int*)(ring + RING_WORDS);

    // 128 blocks x 256 threads (x-plane x y-stripe); plain launch, tagged
    // dataflow sync. Co-residency by capacity (128 blocks << 256 CUs).
    BEMNA_V7_2_PhaseSpace_44117904064519_kernel<<<dim3(NBLOCKS), dim3(NTHREADS), 0, stream>>>(
        D, sx, sy, sz, ex, ey, ez, maxit, out, ring, flags);

    // one float4 lane per slice element: STEP_STRIDE/4 = 49152 threads
    const int total4 = out_size / 4;
    fill_kernel<<<dim3((STEP_STRIDE / 4) / 256), dim3(256), 0, stream>>>(
        flags, (float4*)out, total4);
}